// Round 1
// baseline (541.613 us; speedup 1.0000x reference)
//
#include <hip/hip_runtime.h>
#include <math.h>

#define TILE 32
#define HALO 5
#define IH   42      // TILE + 2*HALO rows of h-conv results
#define HBW2 68      // interleaved-pair row stride: 64 data floats + 4 pad
#define HBW1 36      // hb4 row stride (float4-aligned: 144 B)

__global__ void zero_kernel(float* ws) {
    ws[0] = 0.0f;                 // partial-sum accumulator
    ((unsigned*)ws)[1] = 0u;      // block completion counter
}

// block = 256 threads, tile = 32x32 outputs, 3-channel loop.
// LDS = hb only (28.9 KB) -> 5 blocks/CU (20 waves, 62.5% occupancy).
// __launch_bounds__(256,5): 5 waves/EU -> VGPR cap ~102 (live set ~80).
__global__ __launch_bounds__(256, 5) void ssim_kernel(
    const float* __restrict__ img1, const float* __restrict__ img2,
    const float* __restrict__ window, float* __restrict__ ws,
    float* __restrict__ out,
    int H, int W, float inv_n, unsigned nblocks)
{
    // h-conv results, quantity-paired so Stage C reads b64 instead of 2x b32:
    // hb01[r][2j+0/1] = (h_mu1, h_mu2), hb23 = (h_x2, h_y2), hb4 = h_xy
    __shared__ float hb01[IH][HBW2];
    __shared__ float hb23[IH][HBW2];
    __shared__ float hb4 [IH][HBW1];
    __shared__ float wsum[4];

    const int tid = threadIdx.x;
    const int x0  = blockIdx.x * TILE;
    const int y0  = blockIdx.y * TILE;

    // Recover separable 1D Gaussian: g[j] = w2d[5][j] / sqrt(w2d[5][5])
    float gr[11];
    {
        float inv = 1.0f / sqrtf(window[60]);
        #pragma unroll
        for (int t = 0; t < 11; ++t) gr[t] = window[55 + t] * inv;
    }

    // Fused loads touch gx in [x0-5, x0+36], gh in [y0-5, y0+36].
    // Interior (94% of blocks at 2048^2): no bounds checks, immediate-offset loads.
    const bool interior = (x0 >= HALO) && (x0 + 37 <= W) &&
                          (y0 >= HALO) && (y0 + 37 <= H);

    float acc = 0.0f;

    for (int c = 0; c < 3; ++c) {
        __syncthreads();   // prev-iter Stage C readers done before hb rewrite

        // ---------- Fused Stage AB: global->reg loads + horizontal conv ----------
        // item = (row r of 42) x (4-col group j4 of 8); 336 items, <=2 iters/thread.
        for (int item = tid; item < IH * 8; item += 256) {
            int r   = item >> 3;
            int j4  = (item & 7) << 2;
            int gh  = y0 + r  - HALO;
            int gx0 = x0 + j4 - HALO;

            float xv[14], yv[14];
            if (interior) {
                // one 64-bit address per image; 14 dword loads with imm offsets
                long base = ((long)gh * W + gx0) * 3 + c;   // HWC layout
                const float* p1 = img1 + base;
                const float* p2 = img2 + base;
                #pragma unroll
                for (int k = 0; k < 14; ++k) {
                    xv[k] = p1[k * 3];
                    yv[k] = p2[k * 3];
                }
            } else {
                bool rowok = ((unsigned)gh < (unsigned)H);
                #pragma unroll
                for (int k = 0; k < 14; ++k) {
                    int gx = gx0 + k;
                    bool ok = rowok && ((unsigned)gx < (unsigned)W);
                    long off = ((long)gh * W + gx) * 3 + c;
                    xv[k] = ok ? img1[off] : 0.0f;
                    yv[k] = ok ? img2[off] : 0.0f;
                }
            }

            // h-conv of {x, y, x^2, y^2, xy}; products transient (reg pressure).
            // Per-output accumulation order identical to previous kernel (bitexact).
            float h0[4] = {0,0,0,0}, h1[4] = {0,0,0,0}, h2[4] = {0,0,0,0};
            float h3[4] = {0,0,0,0}, h4[4] = {0,0,0,0};
            #pragma unroll
            for (int t = 0; t < 14; ++t) {
                float a = xv[t], b = yv[t];
                float aa = a * a, bb = b * b, ab = a * b;
                #pragma unroll
                for (int jj = 0; jj < 4; ++jj) {
                    int k = t - jj;
                    if (k >= 0 && k <= 10) {      // static after unroll
                        float g = gr[k];
                        h0[jj] += g * a;  h1[jj] += g * b;
                        h2[jj] += g * aa; h3[jj] += g * bb; h4[jj] += g * ab;
                    }
                }
            }
            *(float4*)&hb01[r][2*j4]     = make_float4(h0[0], h1[0], h0[1], h1[1]);
            *(float4*)&hb01[r][2*j4 + 4] = make_float4(h0[2], h1[2], h0[3], h1[3]);
            *(float4*)&hb23[r][2*j4]     = make_float4(h2[0], h3[0], h2[1], h3[1]);
            *(float4*)&hb23[r][2*j4 + 4] = make_float4(h2[2], h3[2], h2[3], h3[3]);
            *(float4*)&hb4 [r][j4]       = make_float4(h4[0], h4[1], h4[2], h4[3]);
        }
        __syncthreads();

        // ---------- Stage C: vertical conv + SSIM, 4 rows x 1 col per thread ----------
        {
            int j  = tid & 31;
            int i0 = (tid >> 5) * 4;
            float m1[4]  = {0,0,0,0}, m2[4]  = {0,0,0,0};
            float v11[4] = {0,0,0,0}, v22[4] = {0,0,0,0}, v12[4] = {0,0,0,0};
            #pragma unroll
            for (int t = 0; t < 14; ++t) {
                float2 p01 = *(const float2*)&hb01[i0 + t][2 * j];
                float2 p23 = *(const float2*)&hb23[i0 + t][2 * j];
                float  p4  = hb4[i0 + t][j];
                #pragma unroll
                for (int o = 0; o < 4; ++o) {
                    int k = t - o;
                    if (k >= 0 && k <= 10) {      // static after unroll
                        float g = gr[k];
                        m1[o]  += g * p01.x;  m2[o]  += g * p01.y;
                        v11[o] += g * p23.x;  v22[o] += g * p23.y;
                        v12[o] += g * p4;
                    }
                }
            }
            const float C1 = 0.0001f, C2 = 0.0009f;
            #pragma unroll
            for (int o = 0; o < 4; ++o) {
                int gy = y0 + i0 + o, gx = x0 + j;
                if (gy < H && gx < W) {
                    float mu1 = m1[o], mu2 = m2[o];
                    float mu11 = mu1 * mu1, mu22 = mu2 * mu2, mu12 = mu1 * mu2;
                    float s11 = v11[o] - mu11;
                    float s22 = v22[o] - mu22;
                    float s12 = v12[o] - mu12;
                    float num = (2.0f * mu12 + C1) * (2.0f * s12 + C2);
                    float den = (mu11 + mu22 + C1) * (s11 + s22 + C2);
                    acc += num / den;
                }
            }
        }
    }

    // ---------- block reduction + fused finalize ----------
    #pragma unroll
    for (int off = 32; off > 0; off >>= 1)
        acc += __shfl_down(acc, off, 64);
    int lane = tid & 63, wid = tid >> 6;
    if (lane == 0) wsum[wid] = acc;
    __syncthreads();
    if (tid == 0) {
        float bsum = wsum[0] + wsum[1] + wsum[2] + wsum[3];
        atomicAdd(ws, bsum);
        __threadfence();
        unsigned done = atomicAdd((unsigned*)ws + 1, 1u);
        if (done == nblocks - 1) {          // last block: all adds visible
            __threadfence();
            float s = atomicAdd(ws, 0.0f);  // atomic read of full sum
            out[0] = 1.0f - s * inv_n;
        }
    }
}

extern "C" void kernel_launch(void* const* d_in, const int* in_sizes, int n_in,
                              void* d_out, int out_size, void* d_ws, size_t ws_size,
                              hipStream_t stream) {
    const float* img1   = (const float*)d_in[0];
    const float* img2   = (const float*)d_in[1];
    const float* window = (const float*)d_in[2];
    float* out = (float*)d_out;
    float* ws  = (float*)d_ws;

    // Assume square image: in_sizes[0] = H*W*3
    long hw = (long)in_sizes[0] / 3;
    int W = (int)(sqrt((double)hw) + 0.5);
    int H = (int)(hw / W);

    float inv_n = (float)(1.0 / ((double)H * (double)W * 3.0));

    dim3 grid((W + TILE - 1) / TILE, (H + TILE - 1) / TILE);
    unsigned nblocks = grid.x * grid.y;

    zero_kernel<<<1, 1, 0, stream>>>(ws);
    ssim_kernel<<<grid, 256, 0, stream>>>(img1, img2, window, ws, out,
                                          H, W, inv_n, nblocks);
}

// Round 2
// 365.311 us; speedup vs baseline: 1.4826x; 1.4826x over previous
//
#include <hip/hip_runtime.h>
#include <math.h>

#define TILE 32
#define HALO 5
#define IH   42      // TILE + 2*HALO rows of h-conv results
#define HBW2 68      // interleaved-pair row stride: 64 data floats + 4 pad
#define HBW1 36      // hb4 row stride (float4-aligned: 144 B)

__global__ void zero_kernel(float* ws) {
    ws[0] = 0.0f;                 // partial-sum accumulator
    ((unsigned*)ws)[1] = 0u;      // block completion counter
}

// block = 256 threads, tile = 32x32 outputs, 3-channel loop.
// LDS = hb only (28.9 KB). __launch_bounds__(256,4): VGPR cap 512/4 = 128,
// ABOVE the fused-stage live set (~100) -> no spill (round-1 post-mortem:
// (256,5) capped at ~102, allocator went to 48 VGPR + 266 MB scratch writes).
// 4 blocks/CU (16 waves, 50% occupancy).
__global__ __launch_bounds__(256, 4) void ssim_kernel(
    const float* __restrict__ img1, const float* __restrict__ img2,
    const float* __restrict__ window, float* __restrict__ ws,
    float* __restrict__ out,
    int H, int W, float inv_n, unsigned nblocks)
{
    // h-conv results, quantity-paired so Stage C reads b64 instead of 2x b32:
    // hb01[r][2j+0/1] = (h_mu1, h_mu2), hb23 = (h_x2, h_y2), hb4 = h_xy
    __shared__ float hb01[IH][HBW2];
    __shared__ float hb23[IH][HBW2];
    __shared__ float hb4 [IH][HBW1];
    __shared__ float wsum[4];

    const int tid = threadIdx.x;
    const int x0  = blockIdx.x * TILE;
    const int y0  = blockIdx.y * TILE;

    // Recover separable 1D Gaussian: g[j] = w2d[5][j] / sqrt(w2d[5][5])
    float gr[11];
    {
        float inv = 1.0f / sqrtf(window[60]);
        #pragma unroll
        for (int t = 0; t < 11; ++t) gr[t] = window[55 + t] * inv;
    }

    // Fused loads touch gx in [x0-5, x0+36], gh in [y0-5, y0+36].
    // Interior (94% of blocks at 2048^2): no bounds checks, immediate-offset loads.
    const bool interior = (x0 >= HALO) && (x0 + 37 <= W) &&
                          (y0 >= HALO) && (y0 + 37 <= H);

    float acc = 0.0f;

    for (int c = 0; c < 3; ++c) {
        __syncthreads();   // prev-iter Stage C readers done before hb rewrite

        // ---------- Fused Stage AB: global->reg loads + horizontal conv ----------
        // item = (row r of 42) x (4-col group j4 of 8); 336 items, <=2 iters/thread.
        for (int item = tid; item < IH * 8; item += 256) {
            int r   = item >> 3;
            int j4  = (item & 7) << 2;
            int gh  = y0 + r  - HALO;
            int gx0 = x0 + j4 - HALO;

            float xv[14], yv[14];
            if (interior) {
                // one 64-bit address per image; 14 dword loads with imm offsets
                long base = ((long)gh * W + gx0) * 3 + c;   // HWC layout
                const float* p1 = img1 + base;
                const float* p2 = img2 + base;
                #pragma unroll
                for (int k = 0; k < 14; ++k) {
                    xv[k] = p1[k * 3];
                    yv[k] = p2[k * 3];
                }
            } else {
                bool rowok = ((unsigned)gh < (unsigned)H);
                #pragma unroll
                for (int k = 0; k < 14; ++k) {
                    int gx = gx0 + k;
                    bool ok = rowok && ((unsigned)gx < (unsigned)W);
                    long off = ((long)gh * W + gx) * 3 + c;
                    xv[k] = ok ? img1[off] : 0.0f;
                    yv[k] = ok ? img2[off] : 0.0f;
                }
            }

            // h-conv of {x, y, x^2, y^2, xy}; products transient (reg pressure).
            // Per-output accumulation order identical to round-0 kernel (bitexact).
            float h0[4] = {0,0,0,0}, h1[4] = {0,0,0,0}, h2[4] = {0,0,0,0};
            float h3[4] = {0,0,0,0}, h4[4] = {0,0,0,0};
            #pragma unroll
            for (int t = 0; t < 14; ++t) {
                float a = xv[t], b = yv[t];
                float aa = a * a, bb = b * b, ab = a * b;
                #pragma unroll
                for (int jj = 0; jj < 4; ++jj) {
                    int k = t - jj;
                    if (k >= 0 && k <= 10) {      // static after unroll
                        float g = gr[k];
                        h0[jj] += g * a;  h1[jj] += g * b;
                        h2[jj] += g * aa; h3[jj] += g * bb; h4[jj] += g * ab;
                    }
                }
            }
            *(float4*)&hb01[r][2*j4]     = make_float4(h0[0], h1[0], h0[1], h1[1]);
            *(float4*)&hb01[r][2*j4 + 4] = make_float4(h0[2], h1[2], h0[3], h1[3]);
            *(float4*)&hb23[r][2*j4]     = make_float4(h2[0], h3[0], h2[1], h3[1]);
            *(float4*)&hb23[r][2*j4 + 4] = make_float4(h2[2], h3[2], h2[3], h3[3]);
            *(float4*)&hb4 [r][j4]       = make_float4(h4[0], h4[1], h4[2], h4[3]);
        }
        __syncthreads();

        // ---------- Stage C: vertical conv + SSIM, 4 rows x 1 col per thread ----------
        {
            int j  = tid & 31;
            int i0 = (tid >> 5) * 4;
            float m1[4]  = {0,0,0,0}, m2[4]  = {0,0,0,0};
            float v11[4] = {0,0,0,0}, v22[4] = {0,0,0,0}, v12[4] = {0,0,0,0};
            #pragma unroll
            for (int t = 0; t < 14; ++t) {
                float2 p01 = *(const float2*)&hb01[i0 + t][2 * j];
                float2 p23 = *(const float2*)&hb23[i0 + t][2 * j];
                float  p4  = hb4[i0 + t][j];
                #pragma unroll
                for (int o = 0; o < 4; ++o) {
                    int k = t - o;
                    if (k >= 0 && k <= 10) {      // static after unroll
                        float g = gr[k];
                        m1[o]  += g * p01.x;  m2[o]  += g * p01.y;
                        v11[o] += g * p23.x;  v22[o] += g * p23.y;
                        v12[o] += g * p4;
                    }
                }
            }
            const float C1 = 0.0001f, C2 = 0.0009f;
            #pragma unroll
            for (int o = 0; o < 4; ++o) {
                int gy = y0 + i0 + o, gx = x0 + j;
                if (gy < H && gx < W) {
                    float mu1 = m1[o], mu2 = m2[o];
                    float mu11 = mu1 * mu1, mu22 = mu2 * mu2, mu12 = mu1 * mu2;
                    float s11 = v11[o] - mu11;
                    float s22 = v22[o] - mu22;
                    float s12 = v12[o] - mu12;
                    float num = (2.0f * mu12 + C1) * (2.0f * s12 + C2);
                    float den = (mu11 + mu22 + C1) * (s11 + s22 + C2);
                    acc += num / den;
                }
            }
        }
    }

    // ---------- block reduction + fused finalize ----------
    #pragma unroll
    for (int off = 32; off > 0; off >>= 1)
        acc += __shfl_down(acc, off, 64);
    int lane = tid & 63, wid = tid >> 6;
    if (lane == 0) wsum[wid] = acc;
    __syncthreads();
    if (tid == 0) {
        float bsum = wsum[0] + wsum[1] + wsum[2] + wsum[3];
        atomicAdd(ws, bsum);
        __threadfence();
        unsigned done = atomicAdd((unsigned*)ws + 1, 1u);
        if (done == nblocks - 1) {          // last block: all adds visible
            __threadfence();
            float s = atomicAdd(ws, 0.0f);  // atomic read of full sum
            out[0] = 1.0f - s * inv_n;
        }
    }
}

extern "C" void kernel_launch(void* const* d_in, const int* in_sizes, int n_in,
                              void* d_out, int out_size, void* d_ws, size_t ws_size,
                              hipStream_t stream) {
    const float* img1   = (const float*)d_in[0];
    const float* img2   = (const float*)d_in[1];
    const float* window = (const float*)d_in[2];
    float* out = (float*)d_out;
    float* ws  = (float*)d_ws;

    // Assume square image: in_sizes[0] = H*W*3
    long hw = (long)in_sizes[0] / 3;
    int W = (int)(sqrt((double)hw) + 0.5);
    int H = (int)(hw / W);

    float inv_n = (float)(1.0 / ((double)H * (double)W * 3.0));

    dim3 grid((W + TILE - 1) / TILE, (H + TILE - 1) / TILE);
    unsigned nblocks = grid.x * grid.y;

    zero_kernel<<<1, 1, 0, stream>>>(ws);
    ssim_kernel<<<grid, 256, 0, stream>>>(img1, img2, window, ws, out,
                                          H, W, inv_n, nblocks);
}

// Round 3
// 364.273 us; speedup vs baseline: 1.4868x; 1.0029x over previous
//
#include <hip/hip_runtime.h>
#include <math.h>

#define TILE 32
#define HALO 5
#define IH   42      // TILE + 2*HALO
#define LDSW 44      // sx/sy row stride (42 -> 44 floats, float4-aligned)
#define HBW2 68      // hb01/hb23 row stride: 64 pair floats + 4 pad
#define HBW1 36      // hb4 row stride

__global__ void zero_kernel(float* ws) {
    ws[0] = 0.0f;                 // partial-sum accumulator
    ((unsigned*)ws)[1] = 0u;      // block completion counter
}

// Round-0 proven structure (LDS-staged, 134 us) + three fixes:
//  1) hb pair-packed -> Stage C reads b64 (70 b32 -> 28 b64 + 14 b32)
//  2) T14 prefetch: channel c+1 global loads issued under Stage B/C compute,
//     LDS write overlapped with Stage C; 2 barriers/channel instead of 3
//  3) interior fast path (94% of blocks skip per-element bounds checks)
// LDS = 43.7 KB -> 3 blocks/CU; __launch_bounds__(256,3) -> VGPR cap ~170
// (round-1/2 lesson: cap must sit ABOVE live set or allocator spills).
__global__ __launch_bounds__(256, 3) void ssim_kernel(
    const float* __restrict__ img1, const float* __restrict__ img2,
    const float* __restrict__ window, float* __restrict__ ws,
    float* __restrict__ out,
    int H, int W, float inv_n, unsigned nblocks)
{
    __shared__ float sx[IH][LDSW];
    __shared__ float sy[IH][LDSW];
    __shared__ float hb01[IH][HBW2];   // (h_mu1, h_mu2) interleaved pairs
    __shared__ float hb23[IH][HBW2];   // (h_x2, h_y2) interleaved pairs
    __shared__ float hb4 [IH][HBW1];   // h_xy
    __shared__ float wsum[4];

    const int tid = threadIdx.x;
    const int x0  = blockIdx.x * TILE;
    const int y0  = blockIdx.y * TILE;

    // Recover separable 1D Gaussian: g[j] = w2d[5][j] / sqrt(w2d[5][5])
    float gr[11];
    {
        float inv = 1.0f / sqrtf(window[60]);
        #pragma unroll
        for (int t = 0; t < 11; ++t) gr[t] = window[55 + t] * inv;
    }

    // Stage A touches gx in [x0-5, x0+38] (44 staged cols), gh in [y0-5, y0+36].
    const bool interior = (x0 >= HALO) && (x0 + 39 <= W) &&
                          (y0 >= HALO) && (y0 + 37 <= H);

    // Prefetch registers: 2 grid-stride items x (4 x-vals + 4 y-vals)
    float pfx[2][4], pfy[2][4];

    auto load_regs = [&](int c) {
        #pragma unroll
        for (int it = 0; it < 2; ++it) {
            int item = tid + (it << 8);
            if (item < IH * 11) {
                int r   = item / 11;
                int j4  = (item % 11) * 4;
                int gh  = y0 + r  - HALO;
                int gx0 = x0 + j4 - HALO;
                if (interior) {
                    long base = ((long)gh * W + gx0) * 3 + c;   // HWC
                    const float* p1 = img1 + base;
                    const float* p2 = img2 + base;
                    #pragma unroll
                    for (int k = 0; k < 4; ++k) {
                        pfx[it][k] = p1[k * 3];
                        pfy[it][k] = p2[k * 3];
                    }
                } else {
                    bool rowok = ((unsigned)gh < (unsigned)H);
                    #pragma unroll
                    for (int k = 0; k < 4; ++k) {
                        int gx = gx0 + k;
                        bool ok = rowok && ((unsigned)gx < (unsigned)W);
                        long off = ((long)gh * W + gx) * 3 + c;
                        pfx[it][k] = ok ? img1[off] : 0.0f;
                        pfy[it][k] = ok ? img2[off] : 0.0f;
                    }
                }
            }
        }
    };
    auto store_tile = [&]() {
        #pragma unroll
        for (int it = 0; it < 2; ++it) {
            int item = tid + (it << 8);
            if (item < IH * 11) {
                int r  = item / 11;
                int j4 = (item % 11) * 4;
                *(float4*)&sx[r][j4] =
                    make_float4(pfx[it][0], pfx[it][1], pfx[it][2], pfx[it][3]);
                *(float4*)&sy[r][j4] =
                    make_float4(pfy[it][0], pfy[it][1], pfy[it][2], pfy[it][3]);
            }
        }
    };

    float acc = 0.0f;

    // Prologue: channel 0 into regs, then into LDS.
    load_regs(0);
    store_tile();

    for (int c = 0; c < 3; ++c) {
        __syncthreads();              // sx/sy(c) visible; hb(c-1) readers done

        if (c < 2) load_regs(c + 1);  // VMEM in flight under Stage B + C

        // ---------- Stage B: horizontal conv (5 quantities), 4 cols/thread ----------
        for (int item = tid; item < IH * 8; item += 256) {
            int r  = item >> 3;
            int j4 = (item & 7) * 4;
            float xv[16], yv[16];
            *(float4*)&xv[0]  = *(const float4*)&sx[r][j4];
            *(float4*)&xv[4]  = *(const float4*)&sx[r][j4 + 4];
            *(float4*)&xv[8]  = *(const float4*)&sx[r][j4 + 8];
            *(float4*)&xv[12] = *(const float4*)&sx[r][j4 + 12];
            *(float4*)&yv[0]  = *(const float4*)&sy[r][j4];
            *(float4*)&yv[4]  = *(const float4*)&sy[r][j4 + 4];
            *(float4*)&yv[8]  = *(const float4*)&sy[r][j4 + 8];
            *(float4*)&yv[12] = *(const float4*)&sy[r][j4 + 12];

            float h0[4] = {0,0,0,0}, h1[4] = {0,0,0,0}, h2[4] = {0,0,0,0};
            float h3[4] = {0,0,0,0}, h4[4] = {0,0,0,0};
            #pragma unroll
            for (int t = 0; t < 14; ++t) {
                float a = xv[t], b = yv[t];
                float aa = a * a, bb = b * b, ab = a * b;
                #pragma unroll
                for (int jj = 0; jj < 4; ++jj) {
                    int k = t - jj;
                    if (k >= 0 && k <= 10) {      // static after unroll
                        float g = gr[k];
                        h0[jj] += g * a;  h1[jj] += g * b;
                        h2[jj] += g * aa; h3[jj] += g * bb; h4[jj] += g * ab;
                    }
                }
            }
            *(float4*)&hb01[r][2*j4]     = make_float4(h0[0], h1[0], h0[1], h1[1]);
            *(float4*)&hb01[r][2*j4 + 4] = make_float4(h0[2], h1[2], h0[3], h1[3]);
            *(float4*)&hb23[r][2*j4]     = make_float4(h2[0], h3[0], h2[1], h3[1]);
            *(float4*)&hb23[r][2*j4 + 4] = make_float4(h2[2], h3[2], h2[3], h3[3]);
            *(float4*)&hb4 [r][j4]       = make_float4(h4[0], h4[1], h4[2], h4[3]);
        }
        __syncthreads();              // hb(c) visible; sx/sy(c) readers done

        if (c < 2) store_tile();      // sx/sy(c+1) write overlaps Stage C

        // ---------- Stage C: vertical conv + SSIM, 4 rows x 1 col per thread ----------
        {
            int j  = tid & 31;
            int i0 = (tid >> 5) * 4;
            float m1[4]  = {0,0,0,0}, m2[4]  = {0,0,0,0};
            float v11[4] = {0,0,0,0}, v22[4] = {0,0,0,0}, v12[4] = {0,0,0,0};
            #pragma unroll
            for (int t = 0; t < 14; ++t) {
                float2 p01 = *(const float2*)&hb01[i0 + t][2 * j];
                float2 p23 = *(const float2*)&hb23[i0 + t][2 * j];
                float  p4  = hb4[i0 + t][j];
                #pragma unroll
                for (int o = 0; o < 4; ++o) {
                    int k = t - o;
                    if (k >= 0 && k <= 10) {      // static after unroll
                        float g = gr[k];
                        m1[o]  += g * p01.x;  m2[o]  += g * p01.y;
                        v11[o] += g * p23.x;  v22[o] += g * p23.y;
                        v12[o] += g * p4;
                    }
                }
            }
            const float C1 = 0.0001f, C2 = 0.0009f;
            #pragma unroll
            for (int o = 0; o < 4; ++o) {
                int gy = y0 + i0 + o, gx = x0 + j;
                if (gy < H && gx < W) {
                    float mu1 = m1[o], mu2 = m2[o];
                    float mu11 = mu1 * mu1, mu22 = mu2 * mu2, mu12 = mu1 * mu2;
                    float s11 = v11[o] - mu11;
                    float s22 = v22[o] - mu22;
                    float s12 = v12[o] - mu12;
                    float num = (2.0f * mu12 + C1) * (2.0f * s12 + C2);
                    float den = (mu11 + mu22 + C1) * (s11 + s22 + C2);
                    acc += num / den;
                }
            }
        }
    }

    // ---------- block reduction + fused finalize ----------
    #pragma unroll
    for (int off = 32; off > 0; off >>= 1)
        acc += __shfl_down(acc, off, 64);
    int lane = tid & 63, wid = tid >> 6;
    if (lane == 0) wsum[wid] = acc;
    __syncthreads();
    if (tid == 0) {
        float bsum = wsum[0] + wsum[1] + wsum[2] + wsum[3];
        atomicAdd(ws, bsum);
        __threadfence();
        unsigned done = atomicAdd((unsigned*)ws + 1, 1u);
        if (done == nblocks - 1) {          // last block: all adds visible
            __threadfence();
            float s = atomicAdd(ws, 0.0f);  // atomic read of full sum
            out[0] = 1.0f - s * inv_n;
        }
    }
}

extern "C" void kernel_launch(void* const* d_in, const int* in_sizes, int n_in,
                              void* d_out, int out_size, void* d_ws, size_t ws_size,
                              hipStream_t stream) {
    const float* img1   = (const float*)d_in[0];
    const float* img2   = (const float*)d_in[1];
    const float* window = (const float*)d_in[2];
    float* out = (float*)d_out;
    float* ws  = (float*)d_ws;

    // Assume square image: in_sizes[0] = H*W*3
    long hw = (long)in_sizes[0] / 3;
    int W = (int)(sqrt((double)hw) + 0.5);
    int H = (int)(hw / W);

    float inv_n = (float)(1.0 / ((double)H * (double)W * 3.0));

    dim3 grid((W + TILE - 1) / TILE, (H + TILE - 1) / TILE);
    unsigned nblocks = grid.x * grid.y;

    zero_kernel<<<1, 1, 0, stream>>>(ws);
    ssim_kernel<<<grid, 256, 0, stream>>>(img1, img2, window, ws, out,
                                          H, W, inv_n, nblocks);
}

// Round 4
// 281.584 us; speedup vs baseline: 1.9235x; 1.2937x over previous
//
#include <hip/hip_runtime.h>
#include <math.h>

#define TILE 32
#define HALO 5
#define IH   42      // TILE + 2*HALO
#define LDSW 44      // sx/sy row stride (44 staged cols, float4-aligned)
#define HBW2 68      // hb01/hb23 row stride: 64 pair floats + 4 pad
#define HBW1 36      // hb4 row stride

__global__ void zero_kernel(float* ws) {
    ws[0] = 0.0f;                 // partial-sum accumulator
    ((unsigned*)ws)[1] = 0u;      // block completion counter
}

// Round-0 proven structure (134 us kernel) with exactly two low-risk diffs:
//  1) hb pair-packed -> Stage C reads 28 b64 + 14 b32 instead of 70 b32
//  2) interior fast path in Stage A, written INLINE: loads feed the LDS
//     store in the same loop body -- no register liveness across stages
//     (rounds 1-3 post-mortem: any value held across Stage B spills to
//     scratch; WRITE_SIZE is the tripwire, must stay ~0.1 MB)
// LDS = 43.7 KB -> 3 blocks/CU; __launch_bounds__(256,3) -> VGPR cap ~170.
__global__ __launch_bounds__(256, 3) void ssim_kernel(
    const float* __restrict__ img1, const float* __restrict__ img2,
    const float* __restrict__ window, float* __restrict__ ws,
    float* __restrict__ out,
    int H, int W, float inv_n, unsigned nblocks)
{
    __shared__ float sx[IH][LDSW];
    __shared__ float sy[IH][LDSW];
    __shared__ float hb01[IH][HBW2];   // (h_mu1, h_mu2) interleaved pairs
    __shared__ float hb23[IH][HBW2];   // (h_x2, h_y2) interleaved pairs
    __shared__ float hb4 [IH][HBW1];   // h_xy
    __shared__ float wsum[4];

    const int tid = threadIdx.x;
    const int x0  = blockIdx.x * TILE;
    const int y0  = blockIdx.y * TILE;

    // Recover separable 1D Gaussian: g[j] = w2d[5][j] / sqrt(w2d[5][5])
    float gr[11];
    {
        float inv = 1.0f / sqrtf(window[60]);
        #pragma unroll
        for (int t = 0; t < 11; ++t) gr[t] = window[55 + t] * inv;
    }

    // Stage A touches gx in [x0-5, x0+38], gh in [y0-5, y0+36].
    const bool interior = (x0 >= HALO) && (x0 + 39 <= W) &&
                          (y0 >= HALO) && (y0 + 37 <= H);

    float acc = 0.0f;

    for (int c = 0; c < 3; ++c) {
        __syncthreads();   // prev-iter Stage C (hb readers) done before Stage B rewrites hb

        // ---------- Stage A: load zero-padded input tile for channel c ----------
        for (int item = tid; item < IH * 11; item += 256) {
            int r   = item / 11;
            int j4  = (item % 11) * 4;
            int gh  = y0 + r - HALO;
            int gx0 = x0 + j4 - HALO;
            float vx[4], vy[4];
            if (interior) {
                // one base address; 4 dword loads per image with imm offsets
                long base = ((long)gh * W + gx0) * 3 + c;   // HWC layout
                const float* p1 = img1 + base;
                const float* p2 = img2 + base;
                #pragma unroll
                for (int k = 0; k < 4; ++k) {
                    vx[k] = p1[k * 3];
                    vy[k] = p2[k * 3];
                }
            } else {
                bool rowok = ((unsigned)gh < (unsigned)H);
                #pragma unroll
                for (int k = 0; k < 4; ++k) {
                    int gx = gx0 + k;
                    bool ok = rowok && ((unsigned)gx < (unsigned)W);
                    long off = ((long)gh * W + gx) * 3 + c;
                    vx[k] = ok ? img1[off] : 0.0f;
                    vy[k] = ok ? img2[off] : 0.0f;
                }
            }
            *(float4*)&sx[r][j4] = make_float4(vx[0], vx[1], vx[2], vx[3]);
            *(float4*)&sy[r][j4] = make_float4(vy[0], vy[1], vy[2], vy[3]);
        }
        __syncthreads();

        // ---------- Stage B: horizontal conv (5 quantities), 4 cols/thread ----------
        for (int item = tid; item < IH * 8; item += 256) {
            int r  = item >> 3;
            int j4 = (item & 7) * 4;
            float xv[16], yv[16];
            *(float4*)&xv[0]  = *(const float4*)&sx[r][j4];
            *(float4*)&xv[4]  = *(const float4*)&sx[r][j4 + 4];
            *(float4*)&xv[8]  = *(const float4*)&sx[r][j4 + 8];
            *(float4*)&xv[12] = *(const float4*)&sx[r][j4 + 12];
            *(float4*)&yv[0]  = *(const float4*)&sy[r][j4];
            *(float4*)&yv[4]  = *(const float4*)&sy[r][j4 + 4];
            *(float4*)&yv[8]  = *(const float4*)&sy[r][j4 + 8];
            *(float4*)&yv[12] = *(const float4*)&sy[r][j4 + 12];

            float h0[4] = {0,0,0,0}, h1[4] = {0,0,0,0}, h2[4] = {0,0,0,0};
            float h3[4] = {0,0,0,0}, h4[4] = {0,0,0,0};
            #pragma unroll
            for (int t = 0; t < 14; ++t) {
                float a = xv[t], b = yv[t];
                float aa = a * a, bb = b * b, ab = a * b;
                #pragma unroll
                for (int jj = 0; jj < 4; ++jj) {
                    int k = t - jj;
                    if (k >= 0 && k <= 10) {      // static after unroll
                        float g = gr[k];
                        h0[jj] += g * a;  h1[jj] += g * b;
                        h2[jj] += g * aa; h3[jj] += g * bb; h4[jj] += g * ab;
                    }
                }
            }
            *(float4*)&hb01[r][2*j4]     = make_float4(h0[0], h1[0], h0[1], h1[1]);
            *(float4*)&hb01[r][2*j4 + 4] = make_float4(h0[2], h1[2], h0[3], h1[3]);
            *(float4*)&hb23[r][2*j4]     = make_float4(h2[0], h3[0], h2[1], h3[1]);
            *(float4*)&hb23[r][2*j4 + 4] = make_float4(h2[2], h3[2], h2[3], h3[3]);
            *(float4*)&hb4 [r][j4]       = make_float4(h4[0], h4[1], h4[2], h4[3]);
        }
        __syncthreads();

        // ---------- Stage C: vertical conv + SSIM, 4 rows x 1 col per thread ----------
        {
            int j  = tid & 31;
            int i0 = (tid >> 5) * 4;
            float m1[4]  = {0,0,0,0}, m2[4]  = {0,0,0,0};
            float v11[4] = {0,0,0,0}, v22[4] = {0,0,0,0}, v12[4] = {0,0,0,0};
            #pragma unroll
            for (int t = 0; t < 14; ++t) {
                float2 p01 = *(const float2*)&hb01[i0 + t][2 * j];
                float2 p23 = *(const float2*)&hb23[i0 + t][2 * j];
                float  p4  = hb4[i0 + t][j];
                #pragma unroll
                for (int o = 0; o < 4; ++o) {
                    int k = t - o;
                    if (k >= 0 && k <= 10) {      // static after unroll
                        float g = gr[k];
                        m1[o]  += g * p01.x;  m2[o]  += g * p01.y;
                        v11[o] += g * p23.x;  v22[o] += g * p23.y;
                        v12[o] += g * p4;
                    }
                }
            }
            const float C1 = 0.0001f, C2 = 0.0009f;
            #pragma unroll
            for (int o = 0; o < 4; ++o) {
                int gy = y0 + i0 + o, gx = x0 + j;
                if (gy < H && gx < W) {
                    float mu1 = m1[o], mu2 = m2[o];
                    float mu11 = mu1 * mu1, mu22 = mu2 * mu2, mu12 = mu1 * mu2;
                    float s11 = v11[o] - mu11;
                    float s22 = v22[o] - mu22;
                    float s12 = v12[o] - mu12;
                    float num = (2.0f * mu12 + C1) * (2.0f * s12 + C2);
                    float den = (mu11 + mu22 + C1) * (s11 + s22 + C2);
                    acc += num / den;
                }
            }
        }
    }

    // ---------- block reduction + fused finalize ----------
    #pragma unroll
    for (int off = 32; off > 0; off >>= 1)
        acc += __shfl_down(acc, off, 64);
    int lane = tid & 63, wid = tid >> 6;
    if (lane == 0) wsum[wid] = acc;
    __syncthreads();
    if (tid == 0) {
        float bsum = wsum[0] + wsum[1] + wsum[2] + wsum[3];
        atomicAdd(ws, bsum);
        __threadfence();
        unsigned done = atomicAdd((unsigned*)ws + 1, 1u);
        if (done == nblocks - 1) {          // last block: all adds visible
            __threadfence();
            float s = atomicAdd(ws, 0.0f);  // atomic read of full sum
            out[0] = 1.0f - s * inv_n;
        }
    }
}

extern "C" void kernel_launch(void* const* d_in, const int* in_sizes, int n_in,
                              void* d_out, int out_size, void* d_ws, size_t ws_size,
                              hipStream_t stream) {
    const float* img1   = (const float*)d_in[0];
    const float* img2   = (const float*)d_in[1];
    const float* window = (const float*)d_in[2];
    float* out = (float*)d_out;
    float* ws  = (float*)d_ws;

    // Assume square image: in_sizes[0] = H*W*3
    long hw = (long)in_sizes[0] / 3;
    int W = (int)(sqrt((double)hw) + 0.5);
    int H = (int)(hw / W);

    float inv_n = (float)(1.0 / ((double)H * (double)W * 3.0));

    dim3 grid((W + TILE - 1) / TILE, (H + TILE - 1) / TILE);
    unsigned nblocks = grid.x * grid.y;

    zero_kernel<<<1, 1, 0, stream>>>(ws);
    ssim_kernel<<<grid, 256, 0, stream>>>(img1, img2, window, ws, out,
                                          H, W, inv_n, nblocks);
}